// Round 1
// baseline (1098.198 us; speedup 1.0000x reference)
//
#include <hip/hip_runtime.h>
#include <math.h>

namespace {
constexpr int B_ = 4;
constexpr int K_ = 8;
constexpr int H_ = 512;
constexpr int W_ = 1024;
constexpr int N_ = H_ * W_;           // 524288 pixels per image
constexpr int M_ = 4096;              // histogram bins over err in [0,2]
constexpr int BK_ = B_ * K_;
constexpr size_t HIST_BYTES = (size_t)BK_ * M_ * 8;  // packed u64: fg<<32 | total

// float-region offsets (in floats), placed after the histogram region
constexpr int CNT_OFF    = 0;
constexpr int SX_OFF     = BK_;
constexpr int SY_OFF     = 2 * BK_;
constexpr int SS_OFF     = 3 * BK_;
constexpr int SS2_OFF    = 4 * BK_;
constexpr int BG_OFF     = 5 * BK_;            // per-image bg seed loss
constexpr int SEEDFG_OFF = BG_OFF + B_;
constexpr int LOV_OFF    = SEEDFG_OFF + BK_;
constexpr int FIN_OFF    = LOV_OFF + BK_;      // 5 floats per (b,k): cx,cy,sexp,counts,var
constexpr int FLOATS_TOTAL = FIN_OFF + 5 * BK_;
}

__device__ __forceinline__ float sigmoidf_(float x) { return 1.0f / (1.0f + expf(-x)); }

// ---------------- Stage 1: per-instance stats + bg seed loss ----------------
__global__ __launch_bounds__(256) void stats_kernel(const float* __restrict__ pred,
                                                    const int* __restrict__ inst,
                                                    const int* __restrict__ lab,
                                                    float* __restrict__ wsf) {
    __shared__ float s_acc[5 * K_ + 1];   // counts,sx,sy,ssig,ssig2 per k + bg
    int tid = threadIdx.x;
    if (tid < 5 * K_ + 1) s_acc[tid] = 0.0f;
    __syncthreads();

    long long idx = (long long)blockIdx.x * blockDim.x + tid;   // b*N + pix
    int b = (int)(idx / N_);              // one b per block (256 | N)
    int pix = (int)(idx % N_);
    int w = pix % W_;
    int h = pix / W_;

    int ins = inst[idx];
    int lb  = lab[idx];
    float sigma = pred[((long long)b * 4 + 2) * N_ + pix];
    float p3    = pred[((long long)b * 4 + 3) * N_ + pix];
    float seed  = sigmoidf_(p3);

    if (lb == 0) atomicAdd(&s_acc[5 * K_], seed * seed);
    if (ins >= 1 && ins <= K_) {
        int k = ins - 1;
        float xm = 2.0f * (float)w / 2047.0f;   // linspace(0,2,2048)[w]
        float ym = (float)h / 1023.0f;          // linspace(0,1,1024)[h]
        atomicAdd(&s_acc[k], 1.0f);
        atomicAdd(&s_acc[K_ + k], xm);
        atomicAdd(&s_acc[2 * K_ + k], ym);
        atomicAdd(&s_acc[3 * K_ + k], sigma);
        atomicAdd(&s_acc[4 * K_ + k], sigma * sigma);
    }
    __syncthreads();
    if (tid < 5 * K_ + 1) {
        float v = s_acc[tid];
        if (v != 0.0f) {
            int slot;
            if (tid < 5 * K_) {
                int grp = tid / K_, k = tid % K_;
                slot = grp * BK_ + b * K_ + k;
            } else {
                slot = BG_OFF + b;
            }
            atomicAdd(&wsf[slot], v);
        }
    }
}

// ---------------- Stage 2: finalize per-instance params ----------------
__global__ void finalize_kernel(float* __restrict__ wsf) {
    int i = threadIdx.x;
    if (i >= BK_) return;
    float counts = wsf[CNT_OFF + i];
    float cnt = fmaxf(counts, 1.0f);
    float cx = wsf[SX_OFF + i] / cnt;
    float cy = wsf[SY_OFF + i] / cnt;
    float smean = wsf[SS_OFF + i] / cnt;
    float var = wsf[SS2_OFF + i] / cnt - smean * smean;  // E[s^2]-mean^2 == ref forward value
    float sexp = expf(10.0f * smean);
    float* fin = wsf + FIN_OFF + i * 5;
    fin[0] = cx; fin[1] = cy; fin[2] = sexp; fin[3] = counts; fin[4] = var;
}

// ---------------- Stage 3: dist per (pixel,k) -> error histograms + seed_fg ----------------
__global__ __launch_bounds__(256) void hist_kernel(const float* __restrict__ pred,
                                                   const int* __restrict__ inst,
                                                   float* __restrict__ wsf,
                                                   unsigned long long* __restrict__ hist) {
    __shared__ float s_cx[K_], s_cy[K_], s_sexp[K_], s_cnt[K_], s_fg[K_];
    int tid = threadIdx.x;
    long long idx = (long long)blockIdx.x * blockDim.x + tid;
    int b = (int)(idx / N_);
    if (tid < K_) {
        const float* fin = wsf + FIN_OFF + (b * K_ + tid) * 5;
        s_cx[tid] = fin[0]; s_cy[tid] = fin[1];
        s_sexp[tid] = fin[2]; s_cnt[tid] = fin[3];
        s_fg[tid] = 0.0f;
    }
    __syncthreads();

    int pix = (int)(idx % N_);
    int w = pix % W_, h = pix / W_;
    float p0 = pred[((long long)b * 4 + 0) * N_ + pix];
    float p1 = pred[((long long)b * 4 + 1) * N_ + pix];
    float p3 = pred[((long long)b * 4 + 3) * N_ + pix];
    int ins = inst[idx];
    float sex = tanhf(p0) + 2.0f * (float)w / 2047.0f;
    float sey = tanhf(p1) + (float)h / 1023.0f;
    float seed = sigmoidf_(p3);

    unsigned long long* hb = hist + (long long)b * K_ * M_;
#pragma unroll
    for (int k = 0; k < K_; k++) {
        if (s_cnt[k] > 0.0f) {
            float dx = sex - s_cx[k];
            float dy = sey - s_cy[k];
            float dist = expf(-s_sexp[k] * (dx * dx + dy * dy));
            bool fg = (ins == k + 1);
            float err = fg ? (2.0f - 2.0f * dist) : (2.0f * dist);
            int bin = (int)(err * (float)(M_ / 2));
            bin = bin < 0 ? 0 : (bin > M_ - 1 ? M_ - 1 : bin);
            unsigned long long add = fg ? ((1ull << 32) | 1ull) : 1ull;
            atomicAdd(&hb[(long long)k * M_ + bin], add);
            if (fg) {
                float d = seed - dist;
                atomicAdd(&s_fg[k], d * d);
            }
        }
    }
    __syncthreads();
    if (tid < K_ && s_fg[tid] != 0.0f)
        atomicAdd(&wsf[SEEDFG_OFF + b * K_ + tid], s_fg[tid]);
}

// ---------------- Stage 4: Lovasz via histogram suffix scan ----------------
// loss = binw * [ 0.5*J_0 + sum_{j=1}^{M-1} J_j ],  J_j = 1-(p-F_j)/(p+R_j-F_j),
// R_j,F_j = suffix sums over bins >= j (exact for values quantized to bin centers).
__global__ __launch_bounds__(256) void lovasz_kernel(const unsigned long long* __restrict__ hist,
                                                     float* __restrict__ wsf) {
    constexpr int CH = M_ / 256;  // 16 bins per thread
    int bk = blockIdx.x;
    int tid = threadIdx.x;
    float p = wsf[CNT_OFF + bk];

    __shared__ unsigned int sn[256], sf[256];
    __shared__ unsigned int rn[256], rf[256];
    __shared__ float sacc[256];

    const unsigned long long* hh = hist + (long long)bk * M_;
    unsigned long long vals[CH];
    unsigned int ln = 0, lf = 0;
    int base = tid * CH;
#pragma unroll
    for (int j = 0; j < CH; j++) {
        unsigned long long v = hh[base + j];
        vals[j] = v;
        ln += (unsigned int)(v & 0xffffffffull);
        lf += (unsigned int)(v >> 32);
    }
    sn[tid] = ln; sf[tid] = lf;
    __syncthreads();
    if (tid == 0) {  // serial suffix scan over 256 chunks (tiny)
        unsigned int an = 0, af = 0;
        for (int t = 255; t >= 0; t--) { rn[t] = an; rf[t] = af; an += sn[t]; af += sf[t]; }
    }
    __syncthreads();

    float acc = 0.0f;
    unsigned int R = rn[tid], F = rf[tid];
    float pp = fmaxf(p, 1.0f);
#pragma unroll
    for (int j = CH - 1; j >= 0; j--) {
        R += (unsigned int)(vals[j] & 0xffffffffull);
        F += (unsigned int)(vals[j] >> 32);
        float J = (R == 0) ? 0.0f : (1.0f - (pp - (float)F) / (pp + (float)(R - F)));
        acc += (base + j == 0) ? 0.5f * J : J;
    }
    sacc[tid] = acc;
    __syncthreads();
    for (int s = 128; s > 0; s >>= 1) {
        if (tid < s) sacc[tid] += sacc[tid + s];
        __syncthreads();
    }
    if (tid == 0)
        wsf[LOV_OFF + bk] = (p > 0.0f) ? sacc[0] * (2.0f / (float)M_) : 0.0f;
}

// ---------------- Stage 5: combine ----------------
__global__ void final_kernel(const float* __restrict__ wsf, float* __restrict__ out) {
    if (threadIdx.x != 0 || blockIdx.x != 0) return;
    float total = 0.0f;
    for (int b = 0; b < B_; b++) {
        float instl = 0.0f, varl = 0.0f, sfg = 0.0f, npres = 0.0f;
        for (int k = 0; k < K_; k++) {
            int i = b * K_ + k;
            if (wsf[CNT_OFF + i] > 0.0f) {
                npres += 1.0f;
                instl += wsf[LOV_OFF + i];
                varl  += wsf[FIN_OFF + i * 5 + 4];
                sfg   += wsf[SEEDFG_OFF + i];
            }
        }
        float objf = fmaxf(npres, 1.0f);
        float seedl = (wsf[BG_OFF + b] + 1.0f * sfg) / (float)N_;
        total += 1.0f * (instl / objf) + 10.0f * (varl / objf) + 1.0f * seedl;
    }
    out[0] = total / (float)B_;
}

extern "C" void kernel_launch(void* const* d_in, const int* in_sizes, int n_in,
                              void* d_out, int out_size, void* d_ws, size_t ws_size,
                              hipStream_t stream) {
    const float* pred = (const float*)d_in[0];
    const int* inst = (const int*)d_in[1];
    const int* lab = (const int*)d_in[2];
    float* out = (float*)d_out;

    unsigned long long* hist = (unsigned long long*)d_ws;
    float* wsf = (float*)((char*)d_ws + HIST_BYTES);

    // zero histograms + accumulators (ws is poisoned 0xAA before each call)
    hipMemsetAsync(d_ws, 0, HIST_BYTES + (size_t)FLOATS_TOTAL * 4, stream);

    int blocks = (B_ * N_) / 256;  // 8192
    stats_kernel<<<blocks, 256, 0, stream>>>(pred, inst, lab, wsf);
    finalize_kernel<<<1, 64, 0, stream>>>(wsf);
    hist_kernel<<<blocks, 256, 0, stream>>>(pred, inst, wsf, hist);
    lovasz_kernel<<<BK_, 256, 0, stream>>>(hist, wsf);
    final_kernel<<<1, 64, 0, stream>>>(wsf, out);
}

// Round 2
// 408.722 us; speedup vs baseline: 2.6869x; 2.6869x over previous
//
#include <hip/hip_runtime.h>
#include <math.h>

namespace {
constexpr int B_ = 4;
constexpr int K_ = 8;
constexpr int H_ = 512;
constexpr int W_ = 1024;
constexpr int N_ = H_ * W_;           // 524288 pixels per image
constexpr int M_ = 2048;              // histogram bins over err in [0,2]
constexpr int BK_ = B_ * K_;
constexpr size_t HIST_BYTES = (size_t)BK_ * M_ * 8;  // packed u64: fg<<32 | total

// float-region offsets (in floats), placed after the histogram region
constexpr int CNT_OFF    = 0;
constexpr int SX_OFF     = BK_;
constexpr int SY_OFF     = 2 * BK_;
constexpr int SS_OFF     = 3 * BK_;
constexpr int SS2_OFF    = 4 * BK_;
constexpr int BG_OFF     = 5 * BK_;            // per-image bg seed loss
constexpr int SEEDFG_OFF = BG_OFF + B_;
constexpr int LOV_OFF    = SEEDFG_OFF + BK_;
constexpr int FIN_OFF    = LOV_OFF + BK_;      // 5 floats per (b,k): cx,cy,sexp,counts,var
constexpr int FLOATS_TOTAL = FIN_OFF + 5 * BK_;

constexpr int STATS_BLOCKS = 256;
constexpr int STATS_CHUNK  = B_ * N_ / STATS_BLOCKS;  // 8192 pixels, one b per block
constexpr int HIST_BLOCKS  = 512;
constexpr int HIST_CHUNK   = B_ * N_ / HIST_BLOCKS;   // 4096 pixels, one b per block
}

__device__ __forceinline__ float sigmoidf_(float x) { return 1.0f / (1.0f + expf(-x)); }

// ---------------- Stage 1: per-instance stats + bg seed loss ----------------
// Register accumulation (41 floats/thread) -> wave shuffle reduce -> global atomics.
__global__ __launch_bounds__(256) void stats_kernel(const float* __restrict__ pred,
                                                    const int* __restrict__ inst,
                                                    const int* __restrict__ lab,
                                                    float* __restrict__ wsf) {
    int tid = threadIdx.x;
    int b = blockIdx.x / (STATS_BLOCKS / B_);                 // 64 blocks per b
    int pix0 = (blockIdx.x % (STATS_BLOCKS / B_)) * STATS_CHUNK;

    const float* sigp = pred + ((long long)b * 4 + 2) * N_;
    const float* p3p  = pred + ((long long)b * 4 + 3) * N_;
    const int*   insp = inst + (long long)b * N_;
    const int*   labp = lab  + (long long)b * N_;

    float acc[41];
#pragma unroll
    for (int i = 0; i < 41; i++) acc[i] = 0.0f;

    for (int i = tid; i < STATS_CHUNK; i += 256) {
        int pix = pix0 + i;
        int w = pix & (W_ - 1);
        int h = pix >> 10;
        float xm = (float)w * (2.0f / 2047.0f);   // linspace(0,2,2048)[w]
        float ym = (float)h * (1.0f / 1023.0f);   // linspace(0,1,1024)[h]
        float s  = sigp[pix];
        float p3 = p3p[pix];
        int ins  = insp[pix];
        int lb   = labp[pix];
        float seed = sigmoidf_(p3);
        if (lb == 0) acc[40] += seed * seed;
#pragma unroll
        for (int k = 0; k < K_; k++) {
            float m = (ins == k + 1) ? 1.0f : 0.0f;
            acc[k]      += m;
            acc[8 + k]  += m * xm;
            acc[16 + k] += m * ym;
            acc[24 + k] += m * s;
            acc[32 + k] += m * s * s;
        }
    }
    // wave reduction (64 lanes)
#pragma unroll
    for (int i = 0; i < 41; i++) {
        float v = acc[i];
#pragma unroll
        for (int off = 32; off; off >>= 1) v += __shfl_down(v, off, 64);
        acc[i] = v;
    }
    if ((tid & 63) == 0) {
#pragma unroll
        for (int k = 0; k < K_; k++) {
            atomicAdd(&wsf[CNT_OFF + b * K_ + k], acc[k]);
            atomicAdd(&wsf[SX_OFF  + b * K_ + k], acc[8 + k]);
            atomicAdd(&wsf[SY_OFF  + b * K_ + k], acc[16 + k]);
            atomicAdd(&wsf[SS_OFF  + b * K_ + k], acc[24 + k]);
            atomicAdd(&wsf[SS2_OFF + b * K_ + k], acc[32 + k]);
        }
        atomicAdd(&wsf[BG_OFF + b], acc[40]);
    }
}

// ---------------- Stage 2: finalize per-instance params ----------------
__global__ void finalize_kernel(float* __restrict__ wsf) {
    int i = threadIdx.x;
    if (i >= BK_) return;
    float counts = wsf[CNT_OFF + i];
    float cnt = fmaxf(counts, 1.0f);
    float cx = wsf[SX_OFF + i] / cnt;
    float cy = wsf[SY_OFF + i] / cnt;
    float smean = wsf[SS_OFF + i] / cnt;
    float var = wsf[SS2_OFF + i] / cnt - smean * smean;  // E[s^2]-mean^2 == ref forward value
    float sexp = expf(10.0f * smean);
    float* fin = wsf + FIN_OFF + i * 5;
    fin[0] = cx; fin[1] = cy; fin[2] = sexp; fin[3] = counts; fin[4] = var;
}

// ---------------- Stage 3: LDS-privatized histograms + seed_fg ----------------
// 64 KB LDS: 8 instances x 2048 bins, packed u32 = (fg<<16 | total).
// Per-block pixel budget 4096 -> per-bin count <= 4096 < 2^16, no overflow.
__global__ __launch_bounds__(256) void hist_kernel(const float* __restrict__ pred,
                                                   const int* __restrict__ inst,
                                                   float* __restrict__ wsf,
                                                   unsigned long long* __restrict__ hist) {
    __shared__ unsigned int hsh[K_ * M_];   // exactly 64 KB
    int tid = threadIdx.x;
    int bpb = HIST_BLOCKS / B_;             // 128 blocks per b
    int b = blockIdx.x / bpb;
    int pix0 = (blockIdx.x % bpb) * HIST_CHUNK;

    for (int i = tid; i < K_ * M_; i += 256) hsh[i] = 0u;

    // per-instance params: uniform-address loads (scalarized by compiler)
    float cx[K_], cy[K_], sxp[K_];
    bool prs[K_];
#pragma unroll
    for (int k = 0; k < K_; k++) {
        const float* fin = wsf + FIN_OFF + (b * K_ + k) * 5;
        cx[k] = fin[0]; cy[k] = fin[1]; sxp[k] = fin[2];
        prs[k] = fin[3] > 0.0f;
    }
    __syncthreads();

    const float* p0p = pred + ((long long)b * 4) * N_;
    const float* p1p = p0p + N_;
    const float* p3p = p0p + 3LL * N_;
    const int* insp = inst + (long long)b * N_;

    float sfg[K_];
#pragma unroll
    for (int k = 0; k < K_; k++) sfg[k] = 0.0f;

    for (int i = tid; i < HIST_CHUNK; i += 256) {
        int pix = pix0 + i;
        int w = pix & (W_ - 1);
        int h = pix >> 10;
        float sex = tanhf(p0p[pix]) + (float)w * (2.0f / 2047.0f);
        float sey = tanhf(p1p[pix]) + (float)h * (1.0f / 1023.0f);
        float seed = sigmoidf_(p3p[pix]);
        int ins = insp[pix];
#pragma unroll
        for (int k = 0; k < K_; k++) {
            if (prs[k]) {
                float dx = sex - cx[k];
                float dy = sey - cy[k];
                float dist = expf(-sxp[k] * (dx * dx + dy * dy));
                bool fg = (ins == k + 1);
                float err = fg ? (2.0f - 2.0f * dist) : (2.0f * dist);
                int bin = (int)(err * (float)(M_ / 2));
                bin = bin < 0 ? 0 : (bin > M_ - 1 ? M_ - 1 : bin);
                atomicAdd(&hsh[k * M_ + bin], fg ? 0x10001u : 1u);
                float d = seed - dist;
                sfg[k] += fg ? d * d : 0.0f;
            }
        }
    }
    __syncthreads();

    // flush nonzero bins to global packed-u64 histograms
    unsigned long long* gh = hist + (long long)b * K_ * M_;
    for (int i = tid; i < K_ * M_; i += 256) {
        unsigned int v = hsh[i];
        if (v)
            atomicAdd(&gh[i], ((unsigned long long)(v >> 16) << 32) |
                              (unsigned long long)(v & 0xffffu));
    }

    // seed_fg: wave shuffle reduce -> global atomic
#pragma unroll
    for (int k = 0; k < K_; k++) {
        float v = sfg[k];
#pragma unroll
        for (int off = 32; off; off >>= 1) v += __shfl_down(v, off, 64);
        if ((tid & 63) == 0 && v != 0.0f)
            atomicAdd(&wsf[SEEDFG_OFF + b * K_ + k], v);
    }
}

// ---------------- Stage 4: Lovasz via histogram suffix scan ----------------
// loss = binw * [ 0.5*J_0 + sum_{j=1}^{M-1} J_j ],  J_j = 1-(p-F_j)/(p+R_j-F_j),
// R_j,F_j = suffix sums over bins >= j (exact for values quantized to bin centers).
__global__ __launch_bounds__(256) void lovasz_kernel(const unsigned long long* __restrict__ hist,
                                                     float* __restrict__ wsf) {
    constexpr int CH = M_ / 256;  // 8 bins per thread
    int bk = blockIdx.x;
    int tid = threadIdx.x;
    float p = wsf[CNT_OFF + bk];

    __shared__ unsigned int sn[256], sf[256];
    __shared__ unsigned int rn[256], rf[256];
    __shared__ float sacc[256];

    const unsigned long long* hh = hist + (long long)bk * M_;
    unsigned long long vals[CH];
    unsigned int ln = 0, lf = 0;
    int base = tid * CH;
#pragma unroll
    for (int j = 0; j < CH; j++) {
        unsigned long long v = hh[base + j];
        vals[j] = v;
        ln += (unsigned int)(v & 0xffffffffull);
        lf += (unsigned int)(v >> 32);
    }
    sn[tid] = ln; sf[tid] = lf;
    __syncthreads();
    if (tid == 0) {  // serial suffix scan over 256 chunks (tiny)
        unsigned int an = 0, af = 0;
        for (int t = 255; t >= 0; t--) { rn[t] = an; rf[t] = af; an += sn[t]; af += sf[t]; }
    }
    __syncthreads();

    float acc = 0.0f;
    unsigned int R = rn[tid], F = rf[tid];
    float pp = fmaxf(p, 1.0f);
#pragma unroll
    for (int j = CH - 1; j >= 0; j--) {
        R += (unsigned int)(vals[j] & 0xffffffffull);
        F += (unsigned int)(vals[j] >> 32);
        float J = (R == 0) ? 0.0f : (1.0f - (pp - (float)F) / (pp + (float)(R - F)));
        acc += (base + j == 0) ? 0.5f * J : J;
    }
    sacc[tid] = acc;
    __syncthreads();
    for (int s = 128; s > 0; s >>= 1) {
        if (tid < s) sacc[tid] += sacc[tid + s];
        __syncthreads();
    }
    if (tid == 0)
        wsf[LOV_OFF + bk] = (p > 0.0f) ? sacc[0] * (2.0f / (float)M_) : 0.0f;
}

// ---------------- Stage 5: combine ----------------
__global__ void final_kernel(const float* __restrict__ wsf, float* __restrict__ out) {
    if (threadIdx.x != 0 || blockIdx.x != 0) return;
    float total = 0.0f;
    for (int b = 0; b < B_; b++) {
        float instl = 0.0f, varl = 0.0f, sfg = 0.0f, npres = 0.0f;
        for (int k = 0; k < K_; k++) {
            int i = b * K_ + k;
            if (wsf[CNT_OFF + i] > 0.0f) {
                npres += 1.0f;
                instl += wsf[LOV_OFF + i];
                varl  += wsf[FIN_OFF + i * 5 + 4];
                sfg   += wsf[SEEDFG_OFF + i];
            }
        }
        float objf = fmaxf(npres, 1.0f);
        float seedl = (wsf[BG_OFF + b] + 1.0f * sfg) / (float)N_;
        total += 1.0f * (instl / objf) + 10.0f * (varl / objf) + 1.0f * seedl;
    }
    out[0] = total / (float)B_;
}

extern "C" void kernel_launch(void* const* d_in, const int* in_sizes, int n_in,
                              void* d_out, int out_size, void* d_ws, size_t ws_size,
                              hipStream_t stream) {
    const float* pred = (const float*)d_in[0];
    const int* inst = (const int*)d_in[1];
    const int* lab = (const int*)d_in[2];
    float* out = (float*)d_out;

    unsigned long long* hist = (unsigned long long*)d_ws;
    float* wsf = (float*)((char*)d_ws + HIST_BYTES);

    // zero histograms + accumulators (ws is poisoned 0xAA before each call)
    hipMemsetAsync(d_ws, 0, HIST_BYTES + (size_t)FLOATS_TOTAL * 4, stream);

    stats_kernel<<<STATS_BLOCKS, 256, 0, stream>>>(pred, inst, lab, wsf);
    finalize_kernel<<<1, 64, 0, stream>>>(wsf);
    hist_kernel<<<HIST_BLOCKS, 256, 0, stream>>>(pred, inst, wsf, hist);
    lovasz_kernel<<<BK_, 256, 0, stream>>>(hist, wsf);
    final_kernel<<<1, 64, 0, stream>>>(wsf, out);
}